// Round 2
// baseline (773.615 us; speedup 1.0000x reference)
//
#include <hip/hip_runtime.h>
#include <hip/hip_bf16.h>

#define LDIM 4096
#define FDIM 64
#define NIT 64   // K-iterations, 64 K-elems each

typedef __attribute__((ext_vector_type(8))) __bf16 bf16x8;
typedef __attribute__((ext_vector_type(4))) float f32x4;

__device__ __forceinline__ unsigned short f2bf(float f) {
    unsigned int u = __float_as_uint(f);
    u += 0x7fffu + ((u >> 16) & 1u);       // round-to-nearest-even
    return (unsigned short)(u >> 16);
}

__device__ __forceinline__ unsigned int pk2bf(float lo, float hi) {
    unsigned int ul = __float_as_uint(lo);
    ul += 0x7fffu + ((ul >> 16) & 1u);
    unsigned int uh = __float_as_uint(hi);
    uh += 0x7fffu + ((uh >> 16) & 1u);
    return (ul >> 16) | (uh & 0xffff0000u);
}

// Kernel 1: hiddenT[b][o][l] = sum_f text[b][l][f] * weight[f][o], stored bf16 bits.
// Transposed so kernel 2's B-fragment reads are contiguous in k.
__global__ __launch_bounds__(256) void hidden_kernel(
    const float* __restrict__ text, const float* __restrict__ weight,
    unsigned short* __restrict__ hT)
{
    const int b  = blockIdx.x & 7;
    const int lc = blockIdx.x >> 3;        // 0..63
    const int l0 = lc * 64;
    __shared__ float sw[64 * 64];          // weight [f][o]
    __shared__ float st[64 * 65];          // text tile [l][f], +1 pad
    const int t = threadIdx.x;
    #pragma unroll
    for (int i = 0; i < 16; ++i) sw[t + i * 256] = weight[t + i * 256];
    const float* tp = text + ((size_t)b * LDIM + l0) * FDIM;
    #pragma unroll
    for (int i = 0; i < 16; ++i) {
        int idx = t + i * 256;
        st[(idx >> 6) * 65 + (idx & 63)] = tp[idx];
    }
    __syncthreads();
    const int l  = t & 63;                 // lane = l -> coalesced bf16 row writes
    const int o0 = (t >> 6) * 16;
    float acc[16];
    #pragma unroll
    for (int i = 0; i < 16; ++i) acc[i] = 0.f;
    for (int f = 0; f < 64; ++f) {
        float tv = st[l * 65 + f];
        #pragma unroll
        for (int i = 0; i < 16; ++i) acc[i] += tv * sw[f * 64 + o0 + i];
    }
    unsigned short* hp = hT + ((size_t)b * FDIM + o0) * LDIM + l0 + l;
    #pragma unroll
    for (int i = 0; i < 16; ++i) hp[(size_t)i * LDIM] = f2bf(acc[i]);
}

// Kernel 2: out[b] = adj[b] @ hidden[b] + bias.  M=4096 N=64 K=4096 per batch.
// One wave owns a 16-row M-strip x all 64 N. No LDS, no barriers: MFMA fragments
// are loaded straight from global (adj, fp32->bf16 in regs) and from L2-resident
// hT. Register double-buffer -> compiler emits partial-vmcnt pipeline per wave.
__global__ __launch_bounds__(256, 2) void gemm_kernel(
    const float* __restrict__ adj, const unsigned short* __restrict__ hT,
    const float* __restrict__ bias, float* __restrict__ out)
{
    const int b  = blockIdx.x & 7;         // batch -> XCD affinity (hT[b] L2-resident)
    const int mb = blockIdx.x >> 3;        // 0..63
    const int w    = threadIdx.x >> 6;
    const int lane = threadIdx.x & 63;
    const int m16  = lane & 15;            // A-frag m / B-frag n / C col
    const int q    = lane >> 4;            // quad: k = q*8 + j

    const int m0 = mb * 64 + w * 16;
    const float* arow = adj + ((size_t)b * LDIM + m0 + m16) * LDIM + q * 8;
    const unsigned short* hrow = hT + ((size_t)b * FDIM + m16) * LDIM + q * 8;

    float4 aL[2][2], aH[2][2];             // [buf][kstep]
    uint4  bf_[2][8];                      // [buf][nf*2+kstep]

    auto loadT = [&](int buf, int kk) {
        #pragma unroll
        for (int ks = 0; ks < 2; ++ks) {
            aL[buf][ks] = *(const float4*)(arow + kk + ks * 32);
            aH[buf][ks] = *(const float4*)(arow + kk + ks * 32 + 4);
        }
        #pragma unroll
        for (int nf = 0; nf < 4; ++nf)
            #pragma unroll
            for (int ks = 0; ks < 2; ++ks)
                bf_[buf][nf * 2 + ks] =
                    *(const uint4*)(hrow + (size_t)nf * 16 * LDIM + kk + ks * 32);
    };

    f32x4 acc[4];
    #pragma unroll
    for (int nf = 0; nf < 4; ++nf) acc[nf] = (f32x4){0.f, 0.f, 0.f, 0.f};

    loadT(0, 0);

    #pragma unroll 2
    for (int it = 0; it < NIT; ++it) {
        const int cur = it & 1, nxt = cur ^ 1;
        const int nk = (it + 1 < NIT) ? (it + 1) * 64 : 0;  // clamp: dummy reload of tile 0
        loadT(nxt, nk);

        #pragma unroll
        for (int ks = 0; ks < 2; ++ks) {
            union { unsigned int u[4]; bf16x8 v; } af;
            af.u[0] = pk2bf(aL[cur][ks].x, aL[cur][ks].y);
            af.u[1] = pk2bf(aL[cur][ks].z, aL[cur][ks].w);
            af.u[2] = pk2bf(aH[cur][ks].x, aH[cur][ks].y);
            af.u[3] = pk2bf(aH[cur][ks].z, aH[cur][ks].w);
            #pragma unroll
            for (int nf = 0; nf < 4; ++nf) {
                union { uint4 u; bf16x8 v; } bv;
                bv.u = bf_[cur][nf * 2 + ks];
                acc[nf] = __builtin_amdgcn_mfma_f32_16x16x32_bf16(af.v, bv.v, acc[nf], 0, 0, 0);
            }
        }
    }

    // epilogue: C/D layout col = lane&15, row = q*4 + reg
    float* obase = out + ((size_t)b * LDIM + m0 + q * 4) * FDIM + m16;
    #pragma unroll
    for (int nf = 0; nf < 4; ++nf) {
        float bv = bias[nf * 16 + m16];
        #pragma unroll
        for (int r = 0; r < 4; ++r)
            obase[(size_t)r * FDIM + nf * 16] = acc[nf][r] + bv;
    }
}

extern "C" void kernel_launch(void* const* d_in, const int* in_sizes, int n_in,
                              void* d_out, int out_size, void* d_ws, size_t ws_size,
                              hipStream_t stream) {
    const float* text   = (const float*)d_in[0];
    const float* adj    = (const float*)d_in[1];
    const float* weight = (const float*)d_in[2];
    const float* bias   = (const float*)d_in[3];
    float* out = (float*)d_out;
    unsigned short* hT = (unsigned short*)d_ws;   // 8*64*4096*2 = 4 MB

    hidden_kernel<<<512, 256, 0, stream>>>(text, weight, hT);
    gemm_kernel<<<512, 256, 0, stream>>>(adj, hT, bias, out);
}